// Round 3
// baseline (535.619 us; speedup 1.0000x reference)
//
#include <hip/hip_runtime.h>
#include <stdint.h>

#define N_TOKENS 4096
#define D_MODEL  1024
#define NUM_EXP  64
#define CAP      512

typedef unsigned short u16;
typedef __bf16 bf16x8 __attribute__((ext_vector_type(8)));
typedef float  f32x4  __attribute__((ext_vector_type(4)));
typedef const __attribute__((address_space(1))) void* as1cvp;
typedef __attribute__((address_space(3))) void*       as3vp;

__device__ __forceinline__ uint32_t f2bf_bits(float f) {
  union { float f; uint32_t u; } c; c.f = f;
  uint32_t u = c.u;
  u += 0x7fffu + ((u >> 16) & 1u);   // RNE
  return u >> 16;
}

// ================= Kernel 1: fused gate GEMM (fp32) + top-2 + softmax + dispatch =================
// 256 blocks x 256 threads; block owns 16 tokens. Also emits xb (bf16 x).
// thread (tt = tid>>4, eg = tid&15) computes fp32 logits for token tt, experts 4eg..4eg+3.
__global__ __launch_bounds__(256) void gate_fused_kernel(
    const float* __restrict__ x, const float* __restrict__ gw,
    u16* __restrict__ xb, int* __restrict__ cnt,
    int* __restrict__ tok, float* __restrict__ wts)
{
  const int t0  = blockIdx.x * 16;
  const int tid = threadIdx.x;
  const int tt = tid >> 4, eg = tid & 15;

  __shared__ float4 xs[16][32];    // 16 tokens x 128 K, XOR-swizzled f4 cols
  __shared__ float4 gws[64][32];   // 64 experts x 128 K, XOR-swizzled
  __shared__ float  lg[16][64];    // logits

  float acc[4] = {0.f, 0.f, 0.f, 0.f};

  for (int kc = 0; kc < 8; ++kc) {
    const int k0 = kc * 128;
    __syncthreads();               // protect LDS reuse from previous chunk's readers
    #pragma unroll
    for (int i = 0; i < 2; ++i) {  // stage x chunk + write bf16 xb
      int idx = tid + i * 256;
      int r = idx >> 5, c = idx & 31;
      float4 v = *(const float4*)&x[(size_t)(t0 + r) * D_MODEL + k0 + c * 4];
      xs[r][c ^ r] = v;
      uint32_t lo = f2bf_bits(v.x) | (f2bf_bits(v.y) << 16);
      uint32_t hi = f2bf_bits(v.z) | (f2bf_bits(v.w) << 16);
      *(uint2*)&xb[(size_t)(t0 + r) * D_MODEL + k0 + c * 4] = make_uint2(lo, hi);
    }
    #pragma unroll
    for (int i = 0; i < 8; ++i) {  // stage gw chunk
      int idx = tid + i * 256;
      int r = idx >> 5, c = idx & 31;
      gws[r][c ^ (r & 31)] = *(const float4*)&gw[(size_t)r * D_MODEL + k0 + c * 4];
    }
    __syncthreads();
    #pragma unroll
    for (int c = 0; c < 32; ++c) { // fp32 dots (fixed order -> stable vs XLA within 1e-6)
      float4 xa = xs[tt][c ^ tt];
      #pragma unroll
      for (int j = 0; j < 4; ++j) {
        int e = eg * 4 + j;
        float4 wv = gws[e][c ^ (e & 31)];
        acc[j] += xa.x * wv.x; acc[j] += xa.y * wv.y;
        acc[j] += xa.z * wv.z; acc[j] += xa.w * wv.w;
      }
    }
  }
  #pragma unroll
  for (int j = 0; j < 4; ++j) lg[tt][eg * 4 + j] = acc[j];
  __syncthreads();

  if (tid < 16) {                  // per-token top-2 + softmax + dispatch
    float b1 = -3.4e38f; int e1 = 0;
    #pragma unroll
    for (int e = 0; e < 64; ++e) { float v = lg[tid][e]; if (v > b1) { b1 = v; e1 = e; } }
    float b2 = -3.4e38f; int e2 = 0;
    #pragma unroll
    for (int e = 0; e < 64; ++e) { float v = lg[tid][e]; if (e != e1 && v > b2) { b2 = v; e2 = e; } }
    float ex = expf(b2 - b1);
    float w1 = 1.0f / (1.0f + ex);
    float w2 = ex   / (1.0f + ex);
    int t = t0 + tid;
    int p = atomicAdd(&cnt[e1], 1);
    if (p < CAP) { tok[e1 * CAP + p] = t; wts[e1 * CAP + p] = w1; }
    p = atomicAdd(&cnt[e2], 1);
    if (p < CAP) { tok[e2 * CAP + p] = t; wts[e2 * CAP + p] = w2; }
  }
}

// ================= Kernel 2: per-expert GEMM, bf16 MFMA, 2-phase pipeline =================
// grid (8 n-tiles, 4 m-tiles, 64 experts), 512 threads (8 waves = 2m x 4n of 64x32 tiles).
// Tile M=128 x N=128 x K-step 64, double-buffered LDS, prefetch-before-compute.
// Epilogue: atomicAdd directly into out (each element gets exactly 2 commutative adds).
__global__ __launch_bounds__(512) void expert_gemm_kernel(
    const u16* __restrict__ xb, const float* __restrict__ ew,
    const int* __restrict__ cnt, const int* __restrict__ tok,
    const float* __restrict__ wts, float* __restrict__ out)
{
  const int e = blockIdx.z;
  int ne = cnt[e]; ne = ne > CAP ? CAP : ne;
  const int m0 = blockIdx.y * 128;
  if (m0 >= ne) return;
  const int n0 = blockIdx.x * 128;
  const int tid = threadIdx.x;
  const int wid = tid >> 6, lane = tid & 63;
  const int wm = wid & 1, wn = wid >> 1;

  __shared__ u16  Alds[2][128 * 64];   // 2 x 16 KB bf16, XOR(row&7) 16B-chunk swizzle
  __shared__ u16  Blds[2][128 * 64];   // 2 x 16 KB
  __shared__ int   tokL[128];
  __shared__ float wL[128];

  if (tid < 128) {
    int g = m0 + tid;
    bool v = g < ne;
    tokL[tid] = v ? tok[e * CAP + g] : 0;    // pad rows read token 0 (finite, discarded)
    wL[tid]   = v ? wts[e * CAP + g] : 0.f;
  }
  __syncthreads();

  // A-staging sources (pre-swizzled cols so linear global_load_lds dest + XOR'd read match)
  const u16* asrc[2];
  #pragma unroll
  for (int i = 0; i < 2; ++i) {
    int idx = tid + i * 512;
    int r = idx >> 3, c = idx & 7;
    asrc[i] = xb + (size_t)tokL[r] * D_MODEL + (c ^ (r & 7)) * 8;
  }
  // B-staging: 4 float4/thread; precompute source ptrs and swizzled LDS byte offsets
  const float* Wb = ew + (size_t)e * D_MODEL * D_MODEL + (size_t)n0 * D_MODEL;
  const float* bsrc[4]; int boff[4];
  #pragma unroll
  for (int i = 0; i < 4; ++i) {
    int idx = tid + i * 512;
    int r = idx >> 4, c = idx & 15;
    bsrc[i] = Wb + (size_t)r * D_MODEL + c * 4;
    boff[i] = r * 128 + (((c >> 1) ^ (r & 7)) << 4) + (c & 1) * 8;
  }

  // ---- prologue: stage tile 0 into buffer 0 ----
  #pragma unroll
  for (int i = 0; i < 2; ++i)
    __builtin_amdgcn_global_load_lds((as1cvp)(asrc[i]),
                                     (as3vp)((char*)&Alds[0][0] + (tid + i * 512) * 16), 16, 0, 0);
  {
    float4 bv[4];
    #pragma unroll
    for (int i = 0; i < 4; ++i) bv[i] = *(const float4*)(bsrc[i]);
    #pragma unroll
    for (int i = 0; i < 4; ++i) {
      uint32_t lo = f2bf_bits(bv[i].x) | (f2bf_bits(bv[i].y) << 16);
      uint32_t hi = f2bf_bits(bv[i].z) | (f2bf_bits(bv[i].w) << 16);
      *(uint2*)((char*)&Blds[0][0] + boff[i]) = make_uint2(lo, hi);
    }
  }
  __syncthreads();

  f32x4 acc[4][2] = {};

  for (int t = 0; t < 16; ++t) {
    const char* ldsA = (const char*)&Alds[t & 1][0];
    const char* ldsB = (const char*)&Blds[t & 1][0];
    char* ldsAn = (char*)&Alds[(t & 1) ^ 1][0];
    char* ldsBn = (char*)&Blds[(t & 1) ^ 1][0];

    // issue next-tile loads FIRST (hide HBM latency under MFMA)
    float4 bv[4];
    if (t < 15) {
      const int kn = (t + 1) * 64;
      #pragma unroll
      for (int i = 0; i < 2; ++i)
        __builtin_amdgcn_global_load_lds((as1cvp)(asrc[i] + kn),
                                         (as3vp)(ldsAn + (tid + i * 512) * 16), 16, 0, 0);
      #pragma unroll
      for (int i = 0; i < 4; ++i) bv[i] = *(const float4*)(bsrc[i] + kn);
    }

    // compute current tile
    #pragma unroll
    for (int kk = 0; kk < 2; ++kk) {
      const int kbyte = kk * 64 + (lane >> 4) * 16;
      bf16x8 a[4], b[2];
      #pragma unroll
      for (int mi = 0; mi < 4; ++mi) {
        int r = wm * 64 + mi * 16 + (lane & 15);
        a[mi] = *(const bf16x8*)(ldsA + r * 128 + (kbyte ^ ((r & 7) << 4)));
      }
      #pragma unroll
      for (int nj = 0; nj < 2; ++nj) {
        int r = wn * 32 + nj * 16 + (lane & 15);
        b[nj] = *(const bf16x8*)(ldsB + r * 128 + (kbyte ^ ((r & 7) << 4)));
      }
      #pragma unroll
      for (int mi = 0; mi < 4; ++mi)
        #pragma unroll
        for (int nj = 0; nj < 2; ++nj)
          acc[mi][nj] = __builtin_amdgcn_mfma_f32_16x16x32_bf16(a[mi], b[nj], acc[mi][nj], 0, 0, 0);
    }

    // late half of B staging: convert + swizzled ds_write (waits vmcnt on bv only)
    if (t < 15) {
      #pragma unroll
      for (int i = 0; i < 4; ++i) {
        uint32_t lo = f2bf_bits(bv[i].x) | (f2bf_bits(bv[i].y) << 16);
        uint32_t hi = f2bf_bits(bv[i].z) | (f2bf_bits(bv[i].w) << 16);
        *(uint2*)(ldsBn + boff[i]) = make_uint2(lo, hi);
      }
    }
    __syncthreads();   // drains gload_lds (vmcnt) + ds_writes (lgkm): next tile ready
  }

  // ---- epilogue: scale by gate weight, accumulate directly into out ----
  #pragma unroll
  for (int mi = 0; mi < 4; ++mi) {
    #pragma unroll
    for (int r4 = 0; r4 < 4; ++r4) {
      int rl = wm * 64 + mi * 16 + (lane >> 4) * 4 + r4;  // C/D: col=lane&15, row=(lane>>4)*4+reg
      if (m0 + rl < ne) {
        float wg = wL[rl];
        size_t dbase = (size_t)tokL[rl] * D_MODEL + n0 + wn * 32 + (lane & 15);
        #pragma unroll
        for (int nj = 0; nj < 2; ++nj)
          unsafeAtomicAdd(&out[dbase + nj * 16], acc[mi][nj][r4] * wg);
      }
    }
  }
}

extern "C" void kernel_launch(void* const* d_in, const int* in_sizes, int n_in,
                              void* d_out, int out_size, void* d_ws, size_t ws_size,
                              hipStream_t stream) {
  const float* x  = (const float*)d_in[0];
  const float* gw = (const float*)d_in[1];
  const float* ew = (const float*)d_in[2];
  float* out = (float*)d_out;
  char* ws = (char*)d_ws;
  int*   cnt = (int*)(ws + 0);            // 64 ints
  int*   tok = (int*)(ws + 1024);         // 64*512 ints
  float* wts = (float*)(ws + 132096);     // 64*512 f32
  u16*   xb  = (u16*)  (ws + 263168);     // 4096*1024 bf16 (8 MB)

  hipMemsetAsync(cnt, 0, 64 * sizeof(int), stream);
  hipMemsetAsync(out, 0, (size_t)N_TOKENS * D_MODEL * sizeof(float), stream);
  gate_fused_kernel<<<256, 256, 0, stream>>>(x, gw, xb, cnt, tok, wts);
  expert_gemm_kernel<<<dim3(8, 4, 64), 512, 0, stream>>>(xb, ew, cnt, tok, wts, out);
}

// Round 4
// 498.998 us; speedup vs baseline: 1.0734x; 1.0734x over previous
//
#include <hip/hip_runtime.h>
#include <stdint.h>

#define N_TOKENS 4096
#define D_MODEL  1024
#define NUM_EXP  64
#define CAP      512

typedef unsigned short u16;
typedef __bf16 bf16x8 __attribute__((ext_vector_type(8)));
typedef float  f32x4  __attribute__((ext_vector_type(4)));
typedef const __attribute__((address_space(1))) void* as1cvp;
typedef __attribute__((address_space(3))) void*       as3vp;

__device__ __forceinline__ uint32_t f2bf_bits(float f) {
  union { float f; uint32_t u; } c; c.f = f;
  uint32_t u = c.u;
  u += 0x7fffu + ((u >> 16) & 1u);   // RNE
  return u >> 16;
}

// ================= Kernel 1: fused gate GEMM (fp32) + top-2 + softmax + dispatch =================
// 512 blocks x 256 threads; block owns 8 tokens. Also emits xb (bf16 x).
// thread (tt = tid>>5, eg = tid&31) computes fp32 logits for token tt, experts 2eg..2eg+1.
__global__ __launch_bounds__(256) void gate_fused_kernel(
    const float* __restrict__ x, const float* __restrict__ gw,
    u16* __restrict__ xb, int* __restrict__ cnt,
    int* __restrict__ tok, float* __restrict__ wts)
{
  const int t0  = blockIdx.x * 8;
  const int tid = threadIdx.x;
  const int tt = tid >> 5, eg = tid & 31;

  __shared__ float4 xs[8][32];     // 8 tokens x 128 K, XOR-swizzled f4 cols
  __shared__ float4 gws[64][32];   // 64 experts x 128 K, XOR-swizzled
  __shared__ float  lg[8][64];     // logits

  float acc[2] = {0.f, 0.f};

  for (int kc = 0; kc < 8; ++kc) {
    const int k0 = kc * 128;
    __syncthreads();               // previous chunk's readers done
    {                              // stage x chunk (1 f4/thread) + write bf16 xb
      int r = tid >> 5, c = tid & 31;
      float4 v = *(const float4*)&x[(size_t)(t0 + r) * D_MODEL + k0 + c * 4];
      xs[r][c ^ r] = v;
      uint32_t lo = f2bf_bits(v.x) | (f2bf_bits(v.y) << 16);
      uint32_t hi = f2bf_bits(v.z) | (f2bf_bits(v.w) << 16);
      *(uint2*)&xb[(size_t)(t0 + r) * D_MODEL + k0 + c * 4] = make_uint2(lo, hi);
    }
    #pragma unroll
    for (int i = 0; i < 8; ++i) {  // stage gw chunk (8 f4/thread)
      int idx = tid + i * 256;
      int r = idx >> 5, c = idx & 31;
      gws[r][c ^ (r & 31)] = *(const float4*)&gw[(size_t)r * D_MODEL + k0 + c * 4];
    }
    __syncthreads();
    #pragma unroll
    for (int c = 0; c < 32; ++c) { // fp32 dots, fixed order (stable vs XLA ~1e-6)
      float4 xa = xs[tt][c ^ tt];
      #pragma unroll
      for (int j = 0; j < 2; ++j) {
        int ee = eg * 2 + j;
        float4 wv = gws[ee][c ^ (ee & 31)];
        acc[j] += xa.x * wv.x; acc[j] += xa.y * wv.y;
        acc[j] += xa.z * wv.z; acc[j] += xa.w * wv.w;
      }
    }
  }
  #pragma unroll
  for (int j = 0; j < 2; ++j) lg[tt][eg * 2 + j] = acc[j];
  __syncthreads();

  if (tid < 8) {                   // per-token top-2 + softmax + dispatch
    float b1 = -3.4e38f; int e1 = 0;
    #pragma unroll
    for (int e = 0; e < 64; ++e) { float v = lg[tid][e]; if (v > b1) { b1 = v; e1 = e; } }
    float b2 = -3.4e38f; int e2 = 0;
    #pragma unroll
    for (int e = 0; e < 64; ++e) { float v = lg[tid][e]; if (e != e1 && v > b2) { b2 = v; e2 = e; } }
    float ex = expf(b2 - b1);
    float w1 = 1.0f / (1.0f + ex);
    float w2 = ex   / (1.0f + ex);
    int t = t0 + tid;
    int p = atomicAdd(&cnt[e1], 1);
    if (p < CAP) { tok[e1 * CAP + p] = t; wts[e1 * CAP + p] = w1; }
    p = atomicAdd(&cnt[e2], 1);
    if (p < CAP) { tok[e2 * CAP + p] = t; wts[e2 * CAP + p] = w2; }
  }
}

// ================= Kernel 2: per-expert GEMM, bf16 MFMA, m97-style 2-barrier =================
// grid (16 n-tiles, 2 m-tiles, 64 experts), 256 threads = 4 waves; wave = 64-row m-stripe x N=64.
// Tile M=256 x N=64 x K-step 64. A bf16 + B fp32 both via global_load_lds (no reg staging);
// B converted bf16 after ds_read. Single LDS buffer, 2 barriers/step, 3 blocks/CU.
// W is fetched exactly once (268 MB). Epilogue: atomicAdd into out (2 adds/element).
__global__ __launch_bounds__(256, 3) void expert_gemm_kernel(
    const u16* __restrict__ xb, const float* __restrict__ ew,
    const int* __restrict__ cnt, const int* __restrict__ tok,
    const float* __restrict__ wts, float* __restrict__ out)
{
  const int e = blockIdx.z;
  int ne = cnt[e]; ne = ne > CAP ? CAP : ne;
  const int m0 = blockIdx.y * 256;
  if (m0 >= ne) return;                       // y=1 safety tile: instant return in practice
  const int nloc = (ne - m0) > 256 ? 256 : (ne - m0);
  const int ner  = (nloc + 63) & ~63;         // staged rows (round up to wave stripe)
  const int n0 = blockIdx.x * 64;
  const int tid = threadIdx.x;
  const int wid = tid >> 6, lane = tid & 63;
  const bool live = (wid * 64) < nloc;        // dead stripes skip compute, not barriers

  __shared__ __align__(16) u16   Alds[256 * 64];  // 32 KB, 128B rows, XOR(r&7) 16B chunks
  __shared__ __align__(16) float Blds[64 * 64];   // 16 KB fp32, 256B rows, XOR(r&7) 32B chunks
  __shared__ int   tokL[256];
  __shared__ float wL[256];

  {
    int g = m0 + tid;
    bool v = g < ne;
    tokL[tid] = v ? tok[e * CAP + g] : 0;     // pad rows read token 0 (finite, discarded)
    wL[tid]   = v ? wts[e * CAP + g] : 0.f;
  }
  __syncthreads();

  // A: 8 chunks/thread, source col pre-swizzled (linear gload_lds dest + XOR read match)
  int arow[8]; const u16* asrc[8];
  #pragma unroll
  for (int i = 0; i < 8; ++i) {
    int idx = tid + i * 256;
    int r = idx >> 3, c = idx & 7;
    arow[i] = r;
    asrc[i] = xb + (size_t)tokL[r] * D_MODEL + (c ^ (r & 7)) * 8;
  }
  // B: 4 chunks/thread, fp32 rows of 256B, swizzle on 32B granule
  const float* Wb = ew + (size_t)e * D_MODEL * D_MODEL;
  const float* bsrc[4];
  #pragma unroll
  for (int i = 0; i < 4; ++i) {
    int idx = tid + i * 256;
    int r = idx >> 4, c16 = idx & 15;
    int c32 = c16 >> 1;
    int cs16 = ((c32 ^ (r & 7)) << 1) | (c16 & 1);
    bsrc[i] = Wb + (size_t)(n0 + r) * D_MODEL + cs16 * 4;
  }

  f32x4 acc[4][4] = {};

  for (int k0 = 0; k0 < D_MODEL; k0 += 64) {
    __syncthreads();                           // previous step's readers done
    #pragma unroll
    for (int i = 0; i < 8; ++i)
      if (arow[i] < ner)
        __builtin_amdgcn_global_load_lds((as1cvp)(asrc[i] + k0),
                                         (as3vp)(Alds + (tid + i * 256) * 8), 16, 0, 0);
    #pragma unroll
    for (int i = 0; i < 4; ++i)
      __builtin_amdgcn_global_load_lds((as1cvp)(bsrc[i] + k0),
                                       (as3vp)((char*)Blds + (tid + i * 256) * 16), 16, 0, 0);
    __syncthreads();                           // drains vmcnt: tile ready

    if (live) {
      #pragma unroll
      for (int kk = 0; kk < 2; ++kk) {
        const int kbyte = kk * 64 + (lane >> 4) * 16;
        bf16x8 a[4], b[4];
        #pragma unroll
        for (int mi = 0; mi < 4; ++mi) {
          int r = wid * 64 + mi * 16 + (lane & 15);
          a[mi] = *(const bf16x8*)((const char*)Alds + r * 128 + (kbyte ^ ((r & 7) << 4)));
        }
        #pragma unroll
        for (int nj = 0; nj < 4; ++nj) {
          int r = nj * 16 + (lane & 15);
          int c32 = kk * 4 + (lane >> 4);
          const float* p = (const float*)((const char*)Blds + r * 256 + ((c32 ^ (r & 7)) << 5));
          f32x4 lo = *(const f32x4*)p;
          f32x4 hi = *(const f32x4*)(p + 4);
          b[nj][0] = (__bf16)lo[0]; b[nj][1] = (__bf16)lo[1];
          b[nj][2] = (__bf16)lo[2]; b[nj][3] = (__bf16)lo[3];
          b[nj][4] = (__bf16)hi[0]; b[nj][5] = (__bf16)hi[1];
          b[nj][6] = (__bf16)hi[2]; b[nj][7] = (__bf16)hi[3];
        }
        #pragma unroll
        for (int mi = 0; mi < 4; ++mi)
          #pragma unroll
          for (int nj = 0; nj < 4; ++nj)
            acc[mi][nj] = __builtin_amdgcn_mfma_f32_16x16x32_bf16(a[mi], b[nj], acc[mi][nj], 0, 0, 0);
      }
    }
  }

  // epilogue: scale by gate weight, accumulate into out (exactly 2 adds per element)
  if (live) {
    #pragma unroll
    for (int mi = 0; mi < 4; ++mi) {
      #pragma unroll
      for (int r4 = 0; r4 < 4; ++r4) {
        int rl = wid * 64 + mi * 16 + (lane >> 4) * 4 + r4;  // C/D: col=lane&15, row=(lane>>4)*4+reg
        if (rl < nloc) {
          float wg = wL[rl];
          size_t dbase = (size_t)tokL[rl] * D_MODEL + n0 + (lane & 15);
          #pragma unroll
          for (int nj = 0; nj < 4; ++nj)
            unsafeAtomicAdd(&out[dbase + nj * 16], acc[mi][nj][r4] * wg);
        }
      }
    }
  }
}

extern "C" void kernel_launch(void* const* d_in, const int* in_sizes, int n_in,
                              void* d_out, int out_size, void* d_ws, size_t ws_size,
                              hipStream_t stream) {
  const float* x  = (const float*)d_in[0];
  const float* gw = (const float*)d_in[1];
  const float* ew = (const float*)d_in[2];
  float* out = (float*)d_out;
  char* ws = (char*)d_ws;
  int*   cnt = (int*)(ws + 0);            // 64 ints
  int*   tok = (int*)(ws + 1024);         // 64*512 ints
  float* wts = (float*)(ws + 132096);     // 64*512 f32
  u16*   xb  = (u16*)  (ws + 263168);     // 4096*1024 bf16 (8 MB)

  hipMemsetAsync(cnt, 0, 64 * sizeof(int), stream);
  hipMemsetAsync(out, 0, (size_t)N_TOKENS * D_MODEL * sizeof(float), stream);
  gate_fused_kernel<<<512, 256, 0, stream>>>(x, gw, xb, cnt, tok, wts);
  expert_gemm_kernel<<<dim3(16, 2, 64), 256, 0, stream>>>(xb, ew, cnt, tok, wts, out);
}